// Round 2
// baseline (122.908 us; speedup 1.0000x reference)
//
#include <hip/hip_runtime.h>
#include <hip/hip_bf16.h>

// KAN harmonic-basis GEMM, v5: barrier-free, LDS-free register-direct A-gen.
// out[b,h] = sum_{d,f} basis(x[b,d])[f] * W[d,f,h] + sum_d b[d,h]
//
// f=0 + bias -> fp32 partials c_part[8][256], summed in GEMM epilogue.
// f=1..10    -> bf16 MFMA GEMM, M=16384, N=256, K=2560.
//
// v5 structure (v4 post-mortem: compiler sank the register pipeline, barrier
// lockstep kept both pipes at 15%):
//   - NO LDS, NO __syncthreads in the GEMM. Each lane generates exactly the
//     16 A-elements (2 i-tiles x 8 d) its own MFMA fragments need, packs with
//     v_cvt_pk_bf16_f32 into bf16x8 fragments, and feeds MFMA directly.
//     Chebyshev recurrence advances between harmonic steps (state: t2c, sc,
//     cc, sp, cp = 80 VGPR). A-gen is duplicated across wc wave pairs (cheap
//     VALU) in exchange for zero LDS traffic and zero barrier drains.
//   - B: depth-4 rolling register prefetch over flat kt = dtile*10+hs; dtile
//     loop fully unrolled so (kt & 3) buffer indices are compile-time.
//   - Waves fully independent -> 2 waves/SIMD TLP + free compiler scheduling.
// prep parallelized 88 -> 328 blocks (kt-blocks split 4-way over dd).

#define BDIM 16384
#define DDIM 256
#define HOUT 256
#define NKT  80
#define BM 64
#define BN 128

typedef __bf16 bf16x8 __attribute__((ext_vector_type(8)));
typedef float floatx4 __attribute__((ext_vector_type(4)));

__device__ __forceinline__ unsigned short f2bf(float f) {
    unsigned int u = __float_as_uint(f);
    return (unsigned short)((u + 0x7FFFu + ((u >> 16) & 1u)) >> 16);
}

__device__ __forceinline__ unsigned int pkbf(float a, float b) {
    __hip_bfloat162 r = __float22bfloat162_rn(make_float2(a, b));
    return *reinterpret_cast<unsigned int*>(&r);
}

// grid 328 x 256 threads.
// blocks [0,320): kt = bid>>2, sub = bid&3:
//   Wfrag[kt][n=t][dd = sub*8 .. +8] = bf16(W[dtile*32+dd][kt%10+1][n])
// blocks [320,328): p = bid-320; c_part[p][h] = sum_{d in p*32..+32} W[d][0][h]+b[d][h]
__global__ void prep_kernel(const float* __restrict__ W, const float* __restrict__ bias,
                            unsigned short* __restrict__ Wfrag, float* __restrict__ c_part) {
    const int bid = blockIdx.x;
    const int t = threadIdx.x;
    if (bid < 4 * NKT) {
        const int kt = bid >> 2;
        const int sub = bid & 3;
        const int dtile = kt / 10;
        const int f = kt - dtile * 10 + 1;
        const int d0 = dtile * 32 + sub * 8;
        const float* wsrc = W + ((size_t)d0 * 11 + f) * 256 + t;
        union { unsigned short s[8]; int4 v; } buf;
#pragma unroll
        for (int dd = 0; dd < 8; ++dd)
            buf.s[dd] = f2bf(wsrc[(size_t)dd * 11 * 256]);
        *(int4*)(Wfrag + ((size_t)kt * 256 + t) * 32 + sub * 8) = buf.v;
    } else {
        const int p = bid - 4 * NKT;
        float acc = 0.f;
#pragma unroll
        for (int dd = 0; dd < 32; ++dd) {
            const int d = p * 32 + dd;
            acc += W[(size_t)(d * 11) * 256 + t] + bias[(size_t)d * 256 + t];
        }
        c_part[p * 256 + t] = acc;
    }
}

__global__ __launch_bounds__(256, 2)
void kan_gemm(const float* __restrict__ x, const unsigned short* __restrict__ Wfrag,
              const float* __restrict__ c_part, float* __restrict__ out) {
    const int t = threadIdx.x;
    const int m0 = blockIdx.x * BM;
    const int h0 = blockIdx.y * BN;

    const int lane = t & 63;
    const int wave = t >> 6;
    const int wr = wave >> 1;        // row half (32 rows)
    const int wc = wave & 1;         // col half (64 cols)
    const int l15 = lane & 15;
    const int koff = lane >> 4;

    floatx4 acc[2][4];
#pragma unroll
    for (int i = 0; i < 2; ++i)
#pragma unroll
        for (int j = 0; j < 4; ++j)
            acc[i][j] = (floatx4){0.f, 0.f, 0.f, 0.f};

    // lane's x rows: i=0 -> m0 + wr*32 + l15, i=1 -> +16; d-slots koff*8..+8
    const float* xr0 = x + (size_t)(m0 + wr * 32 + l15) * DDIM + koff * 8;
    const unsigned short* bbase = Wfrag + (size_t)(h0 + wc * 64 + l15) * 32 + koff * 8;

    // x for dtile 0: [i*2 + half4]
    float4 xc[4];
    xc[0] = *(const float4*)(xr0 + 0);
    xc[1] = *(const float4*)(xr0 + 4);
    xc[2] = *(const float4*)(xr0 + 16 * DDIM + 0);
    xc[3] = *(const float4*)(xr0 + 16 * DDIM + 4);

    // B prologue: flat kt = 0..3 in flight (depth-4 rolling buffer, slot = kt&3)
    bf16x8 bf[4][4];
#pragma unroll
    for (int p = 0; p < 4; ++p)
#pragma unroll
        for (int j = 0; j < 4; ++j)
            bf[p][j] = *(const bf16x8*)(bbase + (size_t)p * 8192 + j * 512);

#pragma unroll
    for (int dtile = 0; dtile < 8; ++dtile) {
        // x prefetch for next dtile (issued early, consumed next iteration)
        float4 xn[4];
        if (dtile < 7) {
            xn[0] = *(const float4*)(xr0 + (dtile + 1) * 32 + 0);
            xn[1] = *(const float4*)(xr0 + (dtile + 1) * 32 + 4);
            xn[2] = *(const float4*)(xr0 + 16 * DDIM + (dtile + 1) * 32 + 0);
            xn[3] = *(const float4*)(xr0 + 16 * DDIM + (dtile + 1) * 32 + 4);
        }

        // ---- gen init: sincos of 16 elems; Chebyshev state ----
        float sc[16], cc[16], sp[16], cp[16], t2c[16];
#pragma unroll
        for (int i = 0; i < 2; ++i)
#pragma unroll
            for (int e = 0; e < 8; ++e) {
                const int g = i * 8 + e;
                const float xv = ((const float*)&xc[i * 2 + (e >> 2)])[e & 3];
                __sincosf(xv, &sc[g], &cc[g]);
                t2c[g] = cc[g] + cc[g];
                sp[g] = 0.f;
                cp[g] = 1.f;
            }

        // ---- fused pack -> MFMA -> prefetch -> recurrence, hs = 0..9 ----
#pragma unroll
        for (int hs = 0; hs < 10; ++hs) {
            const int cur = (dtile * 10 + hs) & 3;   // compile-time (full unroll)
            const float* src = (hs & 1) ? cc : sc;   // even: sin(k), odd: cos(k)

            union { unsigned int u[4]; bf16x8 v; } a0, a1;
#pragma unroll
            for (int p = 0; p < 4; ++p) {
                a0.u[p] = pkbf(src[2 * p], src[2 * p + 1]);
                a1.u[p] = pkbf(src[8 + 2 * p], src[8 + 2 * p + 1]);
            }
#pragma unroll
            for (int j = 0; j < 4; ++j) {
                acc[0][j] = __builtin_amdgcn_mfma_f32_16x16x32_bf16(a0.v, bf[cur][j], acc[0][j], 0, 0, 0);
                acc[1][j] = __builtin_amdgcn_mfma_f32_16x16x32_bf16(a1.v, bf[cur][j], acc[1][j], 0, 0, 0);
            }

            // B refill: flat kt + 4 into the slot just consumed (clamped at tail)
            {
                int ktp = dtile * 10 + hs + 4;
                if (ktp > 79) ktp = 79;
#pragma unroll
                for (int j = 0; j < 4; ++j)
                    bf[cur][j] = *(const bf16x8*)(bbase + (size_t)ktp * 8192 + j * 512);
            }

            // advance Chebyshev after each cos step (except the last)
            if ((hs & 1) && hs < 9) {
#pragma unroll
                for (int g = 0; g < 16; ++g) {
                    const float ns = t2c[g] * sc[g] - sp[g];
                    const float nc = t2c[g] * cc[g] - cp[g];
                    sp[g] = sc[g]; cp[g] = cc[g];
                    sc[g] = ns;   cc[g] = nc;
                }
            }
        }

        if (dtile < 7) {
            xc[0] = xn[0]; xc[1] = xn[1]; xc[2] = xn[2]; xc[3] = xn[3];
        }
    }

    // ---- epilogue: C/D layout col=lane&15, row=(lane>>4)*4+reg ----
    float cj[4];
#pragma unroll
    for (int j = 0; j < 4; ++j) {
        const int col = h0 + wc * 64 + j * 16 + l15;
        float s = 0.f;
#pragma unroll
        for (int p = 0; p < 8; ++p) s += c_part[p * 256 + col];
        cj[j] = s;
    }
#pragma unroll
    for (int i = 0; i < 2; ++i) {
        const int row0 = m0 + wr * 32 + i * 16 + koff * 4;
#pragma unroll
        for (int j = 0; j < 4; ++j) {
            const int col = h0 + wc * 64 + j * 16 + l15;
#pragma unroll
            for (int r = 0; r < 4; ++r)
                out[(size_t)(row0 + r) * HOUT + col] = acc[i][j][r] + cj[j];
        }
    }
}

extern "C" void kernel_launch(void* const* d_in, const int* in_sizes, int n_in,
                              void* d_out, int out_size, void* d_ws, size_t ws_size,
                              hipStream_t stream) {
    const float* x = (const float*)d_in[0];
    const float* W = (const float*)d_in[1];
    const float* b = (const float*)d_in[2];
    float* out = (float*)d_out;

    unsigned short* Wfrag = (unsigned short*)d_ws;                      // 1,310,720 B
    float* c_part = (float*)((char*)d_ws + (size_t)NKT * 256 * 32 * 2); // 8 KB

    prep_kernel<<<4 * NKT + 8, 256, 0, stream>>>(W, b, Wfrag, c_part);
    kan_gemm<<<dim3(BDIM / BM, HOUT / BN), 256, 0, stream>>>(x, Wfrag, c_part, out);
}